// Round 13
// baseline (442.427 us; speedup 1.0000x reference)
//
#include <hip/hip_runtime.h>
#include <hip/hip_bf16.h>
#include <math.h>

#define NN 50000
#define EE 800000
#define ET_ 850000
#define NG 64
#define NB 196    // ceil(NN/256)
#define PB 1024   // pool blocks
#define GB 391    // ceil(NN/128) gemm blocks
#define NBK 196   // buckets (dst>>8)
#define BCAP 5120 // bucket capacity
#define GATB 6144 // gat blocks (grid-stride)

typedef __attribute__((ext_vector_type(8))) short bf16x8;
typedef __attribute__((ext_vector_type(4))) float f32x4;
typedef __attribute__((ext_vector_type(8))) _Float16 h16x8;

// ---- split f32 -> bf16 hi + bf16 lo (RNE both) ----
__device__ __forceinline__ void bsplit(float v, ushort& h, ushort& l){
  unsigned u = __float_as_uint(v);
  unsigned hb = (u + 0x7fffu + ((u >> 16) & 1u)) >> 16;
  h = (ushort)hb;
  float hf = __uint_as_float(hb << 16);
  float r = v - hf;
  unsigned ur = __float_as_uint(r);
  l = (ushort)((ur + 0x7fffu + ((ur >> 16) & 1u)) >> 16);
}

// ---------- W -> fragment-packed W^T hi/lo  AND  ea = W@[a_src|a_dst] (block 64) ----------
__global__ __launch_bounds__(256) void convwa(const float* __restrict__ W,
    const float* __restrict__ as_, const float* __restrict__ ad_,
    ushort* __restrict__ wfrag, ushort* __restrict__ eafrag){
  const int t = threadIdx.x;
  if (blockIdx.x < 64){
    int idx = blockIdx.x*256 + t;   // idx = k*128 + c
    int c = idx & 127, k = idx >> 7;
    float v = W[idx];
    ushort h, lo;
    bsplit(v, h, lo);
    int dest = (((c>>4)*4 + (k>>5))*64 + (((k&31)>>3)<<4 | (c&15)))*8 + (k&7);
    wfrag[dest] = h;
    wfrag[16384 + dest] = lo;
  } else {
    const int kb = t >> 6, l = t & 63;
    const int col = l & 15, krow = (l >> 4) * 8;
    #pragma unroll
    for (int j = 0; j < 8; j++){
      int k = kb*32 + krow + j;
      float v = 0.f;
      if (col < 8){
        int h = col & 3;
        const float* a  = (col < 4) ? (as_ + h*32) : (ad_ + h*32);
        const float* wr = W + (size_t)k*128 + h*32;
        float acc = 0.f;
        #pragma unroll
        for (int c = 0; c < 32; c++) acc += wr[c]*a[c];
        v = acc;
      }
      ushort hi, lo;
      bsplit(v, hi, lo);
      eafrag[(kb*64 + l)*8 + j] = hi;
      eafrag[2048 + (kb*64 + l)*8 + j] = lo;
    }
  }
}

// ---------- fused: [BN+ReLU] -> split-bf16 MFMA GEMM -> H(f16) + logits via MFMA ----------
// X32 non-null for layer 0 (f32 input); Xh non-null for layers 1,2 (f16 y).
__global__ __launch_bounds__(512) void gemm_fused(const float* __restrict__ X32,
    const _Float16* __restrict__ Xh,
    const ushort* __restrict__ wfrag, const ushort* __restrict__ eafrag,
    const float* __restrict__ scale, const float* __restrict__ shift,
    _Float16* __restrict__ H, float* __restrict__ esrc, float* __restrict__ edst, int N){
  __shared__ ushort wl[32768];   // 64 KB: hi [0..16383], lo [16384..]
  const int tid = threadIdx.x;
  #pragma unroll
  for (int i = 0; i < 8; i++){
    int e = (i*512 + tid) * 8;
    *(bf16x8*)(wl + e) = *(const bf16x8*)(wfrag + e);
  }
  const int w  = tid >> 6;
  const int l  = tid & 63;
  const int lr = l & 15;
  const int lg = l >> 4;
  const int lk = lg * 8;
  const int arow = blockIdx.x*128 + w*16 + lr;
  const bool avl = (arow < N);
  const size_t abase = (size_t)(avl ? arow : 0) * 128;
  bf16x8 ahi[4], alo[4];
  #pragma unroll
  for (int kb = 0; kb < 4; kb++){
    float a[8];
    if (avl){
      if (Xh){
        h16x8 xv = *(const h16x8*)(Xh + abase + kb*32 + lk);
        #pragma unroll
        for (int j=0;j<8;j++) a[j] = (float)xv[j];
      } else {
        *(float4*)(a)   = *(const float4*)(X32 + abase + kb*32 + lk);
        *(float4*)(a+4) = *(const float4*)(X32 + abase + kb*32 + lk + 4);
      }
    } else {
      #pragma unroll
      for (int j=0;j<8;j++) a[j] = 0.f;
    }
    if (scale){
      float s[8], b[8];
      *(float4*)(s)   = *(const float4*)(scale + kb*32 + lk);
      *(float4*)(s+4) = *(const float4*)(scale + kb*32 + lk + 4);
      *(float4*)(b)   = *(const float4*)(shift + kb*32 + lk);
      *(float4*)(b+4) = *(const float4*)(shift + kb*32 + lk + 4);
      #pragma unroll
      for (int j=0;j<8;j++) a[j] = fmaxf(fmaf(a[j], s[j], b[j]), 0.f);
    }
    #pragma unroll
    for (int j=0;j<8;j++){
      ushort hh2, ll2;
      bsplit(a[j], hh2, ll2);
      ahi[kb][j] = (short)hh2;
      alo[kb][j] = (short)ll2;
    }
  }
  __syncthreads();
  const int crowb = blockIdx.x*128 + w*16 + lg*4;
  #pragma unroll
  for (int ct = 0; ct < 8; ct++){
    f32x4 acc = {0.f,0.f,0.f,0.f};
    #pragma unroll
    for (int kb = 0; kb < 4; kb++){
      const int fi = ((ct*4 + kb)*64 + l) * 8;
      bf16x8 bhf = *(const bf16x8*)(wl + fi);
      bf16x8 blf = *(const bf16x8*)(wl + 16384 + fi);
      acc = __builtin_amdgcn_mfma_f32_16x16x32_bf16(ahi[kb], bhf, acc, 0, 0, 0);
      acc = __builtin_amdgcn_mfma_f32_16x16x32_bf16(ahi[kb], blf, acc, 0, 0, 0);
      acc = __builtin_amdgcn_mfma_f32_16x16x32_bf16(alo[kb], bhf, acc, 0, 0, 0);
    }
    #pragma unroll
    for (int j = 0; j < 4; j++){
      int r = crowb + j;
      if (r < N) H[(size_t)r*128 + ct*16 + lr] = (_Float16)acc[j];
    }
  }
  // extra ct-tile: logits e = X @ (W a)
  {
    f32x4 acc = {0.f,0.f,0.f,0.f};
    #pragma unroll
    for (int kb = 0; kb < 4; kb++){
      bf16x8 bhf = *(const bf16x8*)(eafrag + (kb*64 + l)*8);
      bf16x8 blf = *(const bf16x8*)(eafrag + 2048 + (kb*64 + l)*8);
      acc = __builtin_amdgcn_mfma_f32_16x16x32_bf16(ahi[kb], bhf, acc, 0, 0, 0);
      acc = __builtin_amdgcn_mfma_f32_16x16x32_bf16(ahi[kb], blf, acc, 0, 0, 0);
      acc = __builtin_amdgcn_mfma_f32_16x16x32_bf16(alo[kb], bhf, acc, 0, 0, 0);
    }
    if (lr < 8){
      #pragma unroll
      for (int j = 0; j < 4; j++){
        int r = crowb + j;
        if (r < N){
          if (lr < 4) esrc[r*4 + lr] = acc[j];
          else        edst[r*4 + lr - 4] = acc[j];
        }
      }
    }
  }
}

// ---------- CSR build v2: bucketed two-level scatter ----------
__global__ __launch_bounds__(256) void bin_scatter(const int* __restrict__ ei,
    int* __restrict__ btail, int2* __restrict__ bkt){
  __shared__ int cnt[NBK];
  __shared__ int base[NBK];
  const int t = threadIdx.x;
  for (int i = t; i < NBK; i += 256) cnt[i] = 0;
  __syncthreads();
  int sv[8], dv[8], bv[8], lr[8];
  const int e0 = blockIdx.x*2048;
  #pragma unroll
  for (int k = 0; k < 8; k++){
    int i = e0 + k*256 + t;
    sv[k] = -1;
    if (i < ET_){
      int s, d;
      if (i < EE){ s = ei[i]; d = ei[EE + i]; } else { s = i - EE; d = s; }
      sv[k] = s; dv[k] = d; bv[k] = d >> 8;
      lr[k] = atomicAdd(&cnt[bv[k]], 1);
    }
  }
  __syncthreads();
  for (int i = t; i < NBK; i += 256){
    int c = cnt[i];
    base[i] = c ? atomicAdd(&btail[i], c) : 0;
  }
  __syncthreads();
  #pragma unroll
  for (int k = 0; k < 8; k++){
    if (sv[k] >= 0){
      int p = base[bv[k]] + lr[k];
      if (p < BCAP) bkt[bv[k]*BCAP + p] = make_int2(sv[k], dv[k]);
    }
  }
}

__global__ __launch_bounds__(256) void bucket_count(const int* __restrict__ btail,
    const int2* __restrict__ bkt, int* __restrict__ cnt){
  __shared__ int c256[256];
  const int b = blockIdx.x, t = threadIdx.x;
  c256[t] = 0; __syncthreads();
  int n = btail[b]; if (n > BCAP) n = BCAP;
  for (int i = t; i < n; i += 256){
    int d = bkt[b*BCAP + i].y;
    atomicAdd(&c256[d & 255], 1);
  }
  __syncthreads();
  int node = b*256 + t;
  if (node < NN) cnt[node] = c256[t];
}

__global__ __launch_bounds__(256) void scan_partial(const int* __restrict__ cnt,
    int* __restrict__ rowptr, int* __restrict__ bsum){
  __shared__ int sh[256];
  const int t = threadIdx.x;
  const int i = blockIdx.x*256 + t;
  int v = (i < NN) ? cnt[i] : 0;
  sh[t] = v; __syncthreads();
  for (int o=1;o<256;o<<=1){
    int u = (t>=o) ? sh[t-o] : 0;
    __syncthreads();
    sh[t] += u;
    __syncthreads();
  }
  if (i < NN) rowptr[i] = sh[t] - v;
  if (t == 255) bsum[blockIdx.x] = sh[255];
}

__global__ __launch_bounds__(256) void scan_bsum(int* __restrict__ bsum){
  __shared__ int sh[256];
  const int t = threadIdx.x;
  int v = (t < NB) ? bsum[t] : 0;
  sh[t] = v; __syncthreads();
  for (int o=1;o<256;o<<=1){
    int u = (t>=o) ? sh[t-o] : 0;
    __syncthreads();
    sh[t] += u;
    __syncthreads();
  }
  if (t < NB) bsum[t] = sh[t] - v;
}

__global__ __launch_bounds__(256) void scan_add(int* __restrict__ rowptr,
    const int* __restrict__ bsum){
  const int i = blockIdx.x*256 + threadIdx.x;
  if (i < NN) rowptr[i] += bsum[blockIdx.x];
  if (i == NN) rowptr[NN] = ET_;
}

__global__ __launch_bounds__(256) void bucket_scatter(const int* __restrict__ btail,
    const int2* __restrict__ bkt, const int* __restrict__ rowptr,
    int* __restrict__ csr_src){
  __shared__ int h256[256];
  const int b = blockIdx.x, t = threadIdx.x;
  int node = b*256 + t;
  h256[t] = (node < NN) ? rowptr[node] : 0;
  __syncthreads();
  int n = btail[b]; if (n > BCAP) n = BCAP;
  for (int i = t; i < n; i += 256){
    int2 e = bkt[b*BCAP + i];
    int pos = atomicAdd(&h256[e.y & 255], 1);
    csr_src[pos] = e.x;
  }
}

// ---------- fused GAT aggregate (grid-stride, 4-deep pipelined gather) + BN partials ----------
__global__ __launch_bounds__(256) void gat_fused(const int* __restrict__ rowptr,
    const int* __restrict__ csr_src, const float* __restrict__ esrc,
    const float* __restrict__ edst, const _Float16* __restrict__ hbuf,
    const float* __restrict__ bias, const int* __restrict__ ntype,
    _Float16* __restrict__ y16, float* __restrict__ bnpart){
  __shared__ int2 pk[4][64][4];   // (src, wt) replicated per head; 8 KB
  const int w    = threadIdx.x >> 6;
  const int lane = threadIdx.x & 63;
  const int e    = lane >> 4;        // edge-in-group 0..3
  const int c8   = lane & 15;        // channel octet
  const int hd   = c8 >> 2;          // head for this lane's channels
  const int2* pg = &pk[w][e][hd];    // +16 int2 per 4-edge group

  float bs[8], bq[8];
  #pragma unroll
  for (int k=0;k<8;k++){ bs[k]=0.f; bq[k]=0.f; }
  const float4 bbA = *(const float4*)(bias + c8*8);
  const float4 bbB = *(const float4*)(bias + c8*8 + 4);

  for (int d = blockIdx.x*4 + w; d < NN; d += GATB*4){
    const int beg = rowptr[d], end = rowptr[d+1];
    const float4 ed4 = *(const float4*)(edst + (size_t)d*4);
    float dn0=0.f, dn1=0.f, dn2=0.f, dn3=0.f;
    float acc[8];
    #pragma unroll
    for (int k=0;k<8;k++) acc[k]=0.f;

    for (int j0 = beg; j0 < end; j0 += 64){
      int j = j0 + lane;
      int s = d;
      float ex0=0.f, ex1=0.f, ex2=0.f, ex3=0.f;
      if (j < end){
        s = csr_src[j];
        float4 es = *(const float4*)(esrc + (size_t)s*4);
        float e0 = es.x + ed4.x; e0 = (e0 > 0.f) ? e0 : 0.2f*e0;
        float e1 = es.y + ed4.y; e1 = (e1 > 0.f) ? e1 : 0.2f*e1;
        float e2 = es.z + ed4.z; e2 = (e2 > 0.f) ? e2 : 0.2f*e2;
        float e3 = es.w + ed4.w; e3 = (e3 > 0.f) ? e3 : 0.2f*e3;
        ex0 = expf(e0); ex1 = expf(e1); ex2 = expf(e2); ex3 = expf(e3);
        dn0 += ex0; dn1 += ex1; dn2 += ex2; dn3 += ex3;
      }
      int4 w0 = make_int4(s, __float_as_int(ex0), s, __float_as_int(ex1));
      int4 w1 = make_int4(s, __float_as_int(ex2), s, __float_as_int(ex3));
      *(int4*)&pk[w][lane][0] = w0;
      *(int4*)&pk[w][lane][2] = w1;
      int cnt2 = end - j0; if (cnt2 > 64) cnt2 = 64;
      const int ngrp = (cnt2 + 3) >> 2;   // padded slots: wt=0, src=d (safe)
      int g = 0;
      for (; g + 4 <= ngrp; g += 4){
        int2 v0 = pg[(g+0)*16];
        int2 v1 = pg[(g+1)*16];
        int2 v2 = pg[(g+2)*16];
        int2 v3 = pg[(g+3)*16];
        h16x8 h0 = *(const h16x8*)(hbuf + (size_t)v0.x*128 + c8*8);
        h16x8 h1 = *(const h16x8*)(hbuf + (size_t)v1.x*128 + c8*8);
        h16x8 h2 = *(const h16x8*)(hbuf + (size_t)v2.x*128 + c8*8);
        h16x8 h3 = *(const h16x8*)(hbuf + (size_t)v3.x*128 + c8*8);
        float w0f = __int_as_float(v0.y);
        float w1f = __int_as_float(v1.y);
        float w2f = __int_as_float(v2.y);
        float w3f = __int_as_float(v3.y);
        #pragma unroll
        for (int k=0;k<8;k++){
          acc[k] = fmaf((float)h0[k], w0f, acc[k]);
          acc[k] = fmaf((float)h1[k], w1f, acc[k]);
          acc[k] = fmaf((float)h2[k], w2f, acc[k]);
          acc[k] = fmaf((float)h3[k], w3f, acc[k]);
        }
      }
      for (; g < ngrp; g++){
        int2 v = pg[g*16];
        float wg = __int_as_float(v.y);
        h16x8 hv = *(const h16x8*)(hbuf + (size_t)v.x*128 + c8*8);
        #pragma unroll
        for (int k=0;k<8;k++) acc[k] = fmaf((float)hv[k], wg, acc[k]);
      }
    }
    #pragma unroll
    for (int o = 32; o; o >>= 1){
      dn0 += __shfl_xor(dn0, o);
      dn1 += __shfl_xor(dn1, o);
      dn2 += __shfl_xor(dn2, o);
      dn3 += __shfl_xor(dn3, o);
    }
    float dsel = (hd==0) ? dn0 : (hd==1) ? dn1 : (hd==2) ? dn2 : dn3;
    float inv = 1.f / (dsel + 1e-16f);
    #pragma unroll
    for (int k=0;k<8;k++){
      acc[k] += __shfl_xor(acc[k], 16);
      acc[k] += __shfl_xor(acc[k], 32);
    }
    if (e == 0){
      float aw = (ntype[d] == 0) ? 1.5f : 1.0f;
      float o8[8];
      o8[0] = (acc[0]*inv + bbA.x) * aw;
      o8[1] = (acc[1]*inv + bbA.y) * aw;
      o8[2] = (acc[2]*inv + bbA.z) * aw;
      o8[3] = (acc[3]*inv + bbA.w) * aw;
      o8[4] = (acc[4]*inv + bbB.x) * aw;
      o8[5] = (acc[5]*inv + bbB.y) * aw;
      o8[6] = (acc[6]*inv + bbB.z) * aw;
      o8[7] = (acc[7]*inv + bbB.w) * aw;
      h16x8 oh;
      #pragma unroll
      for (int k=0;k<8;k++) oh[k] = (_Float16)o8[k];
      *(h16x8*)(y16 + (size_t)d*128 + c8*8) = oh;
      #pragma unroll
      for (int k=0;k<8;k++){ bs[k] += o8[k]; bq[k] += o8[k]*o8[k]; }
    }
  }
  // block-level BN-stat reduce (reuse pk LDS as float[4][16][16])
  __syncthreads();
  float* bnp = (float*)pk;
  if (e == 0){
    float* q = bnp + (w*16 + c8)*16;
    #pragma unroll
    for (int k=0;k<8;k++){ q[k] = bs[k]; q[8+k] = bq[k]; }
  }
  __syncthreads();
  const int t = threadIdx.x;
  const int c = t & 127, stat = t >> 7;
  float v = 0.f;
  #pragma unroll
  for (int ww = 0; ww < 4; ww++)
    v += bnp[(ww*16 + (c>>3))*16 + stat*8 + (c&7)];
  bnpart[(size_t)blockIdx.x*256 + t] = v;
}

// ---------- BN partial reduce ----------
__global__ __launch_bounds__(256) void bn_reduce(const float* __restrict__ bnpart,
    double* __restrict__ bnsum, double* __restrict__ bnsumsq){
  const int t = threadIdx.x, b = blockIdx.x;   // 64 blocks
  float acc = 0.f;
  #pragma unroll 4
  for (int j = 0; j < GATB/64; j++)
    acc += bnpart[(size_t)(b*(GATB/64) + j)*256 + t];
  const int c = t & 127;
  if (t < 128) atomicAdd(bnsum + c, (double)acc);
  else         atomicAdd(bnsumsq + c, (double)acc);
}

// ---------- BN finalize ----------
__global__ void bn_final(const double* __restrict__ bnsum, const double* __restrict__ bnsumsq,
    const float* __restrict__ gma, const float* __restrict__ bta,
    float* __restrict__ scale, float* __restrict__ shift, int N){
  int c = threadIdx.x;
  double mu  = bnsum[c] / N;
  double var = bnsumsq[c] / N - mu*mu;
  if (var < 0.0) var = 0.0;
  float inv = (float)(1.0 / sqrt(var + 1e-5));
  float sc  = inv * gma[c];
  scale[c] = sc;
  shift[c] = bta[c] - (float)mu * sc;
}

// ---------- pool phase 1 (f16 input) ----------
__global__ __launch_bounds__(256) void pool_partial(const _Float16* __restrict__ y16,
    const int* __restrict__ batch, const float* __restrict__ scale,
    const float* __restrict__ shift, float* __restrict__ pooled){
  const int t = threadIdx.x;
  const int c = t & 127;
  const int sub = t >> 7;
  const int per = (NN + PB - 1) / PB;
  const int n0 = blockIdx.x * per;
  int n1 = n0 + per; if (n1 > NN) n1 = NN;
  const float sc = scale[c], sh = shift[c];
  float acc = 0.f;
  int curg = -1;
  for (int n = n0 + sub; n < n1; n += 2){
    int g = batch[n];
    if (g != curg){
      if (curg >= 0) unsafeAtomicAdd(pooled + (size_t)curg*128 + c, acc);
      curg = g; acc = 0.f;
    }
    float v = (float)y16[(size_t)n*128 + c];
    acc += fmaxf(fmaf(v, sc, sh), 0.f);
  }
  if (curg >= 0) unsafeAtomicAdd(pooled + (size_t)curg*128 + c, acc);
}

// ---------- pool phase 2: mean + MLP head ----------
__global__ __launch_bounds__(128) void mlp_head(const float* __restrict__ pooled,
    const int* __restrict__ batch, const float* __restrict__ fc1w,
    const float* __restrict__ fc1b, const float* __restrict__ fc2w,
    const float* __restrict__ fc2b, float* __restrict__ out){
  __shared__ float psh[128];
  __shared__ float hid[32];
  const int g = blockIdx.x, t = threadIdx.x;
  int lo = 0, hi = NN;
  while (lo < hi){ int mid = (lo+hi)>>1; if (batch[mid] < g) lo = mid+1; else hi = mid; }
  const int beg = lo;
  lo = beg; hi = NN;
  while (lo < hi){ int mid = (lo+hi)>>1; if (batch[mid] < g+1) lo = mid+1; else hi = mid; }
  int cntn = lo - beg; if (cntn < 1) cntn = 1;
  psh[t] = pooled[(size_t)g*128 + t] / (float)cntn;
  __syncthreads();
  if (t < 32){
    float a = fc1b[t];
    for (int k=0;k<128;k++) a += psh[k]*fc1w[k*32+t];
    a = (a > 0.f) ? a : 0.f;
    hid[t] = a * fc2w[t];
  }
  __syncthreads();
  if (t == 0){
    float sacc = fc2b[0];
    #pragma unroll
    for (int j=0;j<32;j++) sacc += hid[j];
    out[g] = sacc;
  }
}

extern "C" void kernel_launch(void* const* d_in, const int* in_sizes, int n_in,
                              void* d_out, int out_size, void* d_ws, size_t ws_size,
                              hipStream_t stream){
  const float* x     = (const float*)d_in[0];
  const int*   ei    = (const int*)d_in[1];
  const int*   ntype = (const int*)d_in[2];
  const int*   batch = (const int*)d_in[3];
  const float* Wl[3]  = {(const float*)d_in[4],  (const float*)d_in[10], (const float*)d_in[16]};
  const float* asl[3] = {(const float*)d_in[5],  (const float*)d_in[11], (const float*)d_in[17]};
  const float* adl[3] = {(const float*)d_in[6],  (const float*)d_in[12], (const float*)d_in[18]};
  const float* bl[3]  = {(const float*)d_in[7],  (const float*)d_in[13], (const float*)d_in[19]};
  const float* gl[3]  = {(const float*)d_in[8],  (const float*)d_in[14], (const float*)d_in[20]};
  const float* bel[3] = {(const float*)d_in[9],  (const float*)d_in[15], (const float*)d_in[21]};
  const float* fc1w = (const float*)d_in[22];
  const float* fc1b = (const float*)d_in[23];
  const float* fc2w = (const float*)d_in[24];
  const float* fc2b = (const float*)d_in[25];

  char* base = (char*)d_ws;
  size_t off = 0;
  auto alloc = [&](size_t bytes)->char*{
    size_t o = (off + 255) & ~(size_t)255; off = o + bytes; return base + o;
  };
  _Float16* hbuf = (_Float16*)alloc((size_t)NN*128*2);
  _Float16* y16  = (_Float16*)alloc((size_t)NN*128*2);
  ushort* wfrag  = (ushort*)alloc((size_t)32768*2);
  ushort* eafrag = (ushort*)alloc((size_t)4096*2);
  float* esrc    = (float*)alloc((size_t)NN*4*4);
  float* edst    = (float*)alloc((size_t)NN*4*4);
  int*   cnt     = (int*)  alloc((size_t)NN*4);
  int*   rowptr  = (int*)  alloc((size_t)(NN+1)*4);
  int*   csr_src = (int*)  alloc((size_t)ET_*4);
  int*   btail   = (int*)  alloc((size_t)NBK*4);
  int2*  bkt     = (int2*) alloc((size_t)NBK*BCAP*8);
  int*   bsum    = (int*)  alloc((size_t)NB*4);
  float* bnpart  = (float*)alloc((size_t)GATB*256*4);
  double* bnsum  = (double*)alloc(128*8);
  double* bnsumsq= (double*)alloc(128*8);
  float* scale   = (float*)alloc(128*4);
  float* shift   = (float*)alloc(128*4);
  float* pooled  = (float*)alloc((size_t)NG*128*4);
  if (off > ws_size) return;

  // ---- CSR build v2 (once; reused by all 3 layers) ----
  hipMemsetAsync(btail, 0, (size_t)NBK*4, stream);
  hipMemsetAsync(pooled, 0, (size_t)NG*128*4, stream);
  bin_scatter<<<(ET_+2047)/2048, 256, 0, stream>>>(ei, btail, bkt);
  bucket_count<<<NBK, 256, 0, stream>>>(btail, bkt, cnt);
  scan_partial<<<NB, 256, 0, stream>>>(cnt, rowptr, bsum);
  scan_bsum<<<1, 256, 0, stream>>>(bsum);
  scan_add<<<NB, 256, 0, stream>>>(rowptr, bsum);
  bucket_scatter<<<NBK, 256, 0, stream>>>(btail, bkt, rowptr, csr_src);

  for (int l = 0; l < 3; l++){
    const float*    in32 = (l==0) ? x : nullptr;
    const _Float16* in16 = (l==0) ? nullptr : y16;
    const float* scl = (l==0) ? nullptr : scale;
    const float* shf = (l==0) ? nullptr : shift;
    hipMemsetAsync(bnsum, 0, 128*8*2, stream);
    convwa<<<65, 256, 0, stream>>>(Wl[l], asl[l], adl[l], wfrag, eafrag);
    gemm_fused<<<GB, 512, 0, stream>>>(in32, in16, wfrag, eafrag, scl, shf,
                                       hbuf, esrc, edst, NN);
    gat_fused<<<GATB, 256, 0, stream>>>(rowptr, csr_src, esrc, edst, hbuf,
                                        bl[l], ntype, y16, bnpart);
    bn_reduce<<<64, 256, 0, stream>>>(bnpart, bnsum, bnsumsq);
    bn_final<<<1, 128, 0, stream>>>(bnsum, bnsumsq, gl[l], bel[l], scale, shift, NN);
  }
  pool_partial<<<PB, 256, 0, stream>>>(y16, batch, scale, shift, pooled);
  mlp_head<<<NG, 128, 0, stream>>>(pooled, batch, fc1w, fc1b, fc2w, fc2b, (float*)d_out);
}